// Round 2
// baseline (1524.264 us; speedup 1.0000x reference)
//
#include <hip/hip_runtime.h>
#include <hip/hip_bf16.h>
#include <math.h>

typedef unsigned short u16;
typedef __bf16 bf16x8 __attribute__((ext_vector_type(8)));
typedef float f32x4 __attribute__((ext_vector_type(4)));

#define B_  2
#define S_  2048
#define D_  4096
#define H_  32
#define HD_ 128

__device__ __forceinline__ unsigned rne_bf16(float x) {
  unsigned u = __float_as_uint(x);
  return (u + 0x7fffu + ((u >> 16) & 1u)) >> 16;
}

__device__ __forceinline__ void async16(void* lds, const void* g) {
  __builtin_amdgcn_global_load_lds(
      (__attribute__((address_space(1))) void*)(g),
      (__attribute__((address_space(3))) void*)(lds), 16, 0, 0);
}

// ---------------------------------------------------------------- convert
__global__ __launch_bounds__(256) void convert_bf16(
    const float* __restrict__ src, u16* __restrict__ dst, int n8) {
  int i = blockIdx.x * 256 + threadIdx.x;
  if (i >= n8) return;
  const float4* s = (const float4*)src + (size_t)i * 2;
  float4 a = s[0], b = s[1];
  uint4 o;
  o.x = rne_bf16(a.x) | (rne_bf16(a.y) << 16);
  o.y = rne_bf16(a.z) | (rne_bf16(a.w) << 16);
  o.z = rne_bf16(b.x) | (rne_bf16(b.y) << 16);
  o.w = rne_bf16(b.z) | (rne_bf16(b.w) << 16);
  ((uint4*)dst)[i] = o;
}

// ---------------------------------------------------------------- GEMM (A row-major MxK, B row-major NxK, C = A*B^T)
template <int MODE>
__global__ __launch_bounds__(256) void gemm_bt(
    const u16* __restrict__ A, const u16* __restrict__ Bw,
    u16* __restrict__ outB, float* __restrict__ outF,
    const float* __restrict__ fc, const float* __restrict__ fs) {
  __shared__ u16 As[128 * 32];
  __shared__ u16 Bs[128 * 32];
  const int tid  = threadIdx.x;
  const int lane = tid & 63;
  const int wave = tid >> 6;
  const int lm   = lane & 15, quad = lane >> 4;
  const int m0 = blockIdx.x * 128, n0 = blockIdx.y * 128;
  const int mr = (wave >> 1) * 64, nc = (wave & 1) * 64;
  const int K = 4096;

  const int c0 = tid, c1 = tid + 256;
  const int r0 = c0 >> 2, kc0 = ((c0 & 3) ^ ((c0 >> 4) & 3)) * 8;
  const int r1 = c1 >> 2, kc1 = ((c1 & 3) ^ ((c1 >> 4) & 3)) * 8;
  const u16* Ag0 = A + (size_t)(m0 + r0) * K + kc0;
  const u16* Ag1 = A + (size_t)(m0 + r1) * K + kc1;
  const u16* Bg0 = Bw + (size_t)(n0 + r0) * K + kc0;
  const u16* Bg1 = Bw + (size_t)(n0 + r1) * K + kc1;

  const int koff = (quad ^ ((lm >> 2) & 3)) * 8;

  f32x4 acc[4][4] = {};

  for (int kb = 0; kb < K; kb += 32) {
    async16(&As[c0 * 8], Ag0 + kb);
    async16(&As[c1 * 8], Ag1 + kb);
    async16(&Bs[c0 * 8], Bg0 + kb);
    async16(&Bs[c1 * 8], Bg1 + kb);
    __syncthreads();
    bf16x8 af[4], bfr[4];
#pragma unroll
    for (int i = 0; i < 4; ++i) af[i] = *(const bf16x8*)&As[(mr + i * 16 + lm) * 32 + koff];
#pragma unroll
    for (int j = 0; j < 4; ++j) bfr[j] = *(const bf16x8*)&Bs[(nc + j * 16 + lm) * 32 + koff];
#pragma unroll
    for (int i = 0; i < 4; ++i)
#pragma unroll
      for (int j = 0; j < 4; ++j)
        acc[i][j] = __builtin_amdgcn_mfma_f32_16x16x32_bf16(af[i], bfr[j], acc[i][j], 0, 0, 0);
    __syncthreads();
  }

  if (MODE == 1) {  // RoPE -> [bh][s][d]
#pragma unroll
    for (int i = 0; i < 4; ++i) {
      const int mbase = m0 + mr + i * 16 + quad * 4;
#pragma unroll
      for (int j = 0; j < 4; ++j) {
        const int n = n0 + nc + j * 16 + lm;
        const int h = n >> 7, d = n & 127, ir = d >> 1;
#pragma unroll
        for (int r = 0; r < 4; ++r) {
          const int m = mbase + r;
          const int s = m & (S_ - 1);
          const int bb = m >> 11;
          float v = acc[i][j][r];
          float p = __shfl_xor(v, 1);
          float cv = fc[s * (HD_ / 2) + ir];
          float sv = fs[s * (HD_ / 2) + ir];
          float o = ((lane & 1) == 0) ? (v * cv - p * sv) : (p * sv + v * cv);
          float po = __shfl_xor(o, 1);
          if ((lane & 1) == 0) {
            unsigned pkt = rne_bf16(o) | (rne_bf16(po) << 16);
            size_t idx = (((size_t)(bb * H_ + h) * S_ + s) * HD_ + d) >> 1;
            ((unsigned*)outB)[idx] = pkt;
          }
        }
      }
    }
  } else if (MODE == 3) {  // V^T -> [bh][d][s]
#pragma unroll
    for (int i = 0; i < 4; ++i) {
      const int mbase = m0 + mr + i * 16 + quad * 4;
      const int s0 = mbase & (S_ - 1);
      const int bb = mbase >> 11;
#pragma unroll
      for (int j = 0; j < 4; ++j) {
        const int n = n0 + nc + j * 16 + lm;
        const int h = n >> 7, d = n & 127;
        uint2 pkt;
        pkt.x = rne_bf16(acc[i][j][0]) | (rne_bf16(acc[i][j][1]) << 16);
        pkt.y = rne_bf16(acc[i][j][2]) | (rne_bf16(acc[i][j][3]) << 16);
        size_t idx = ((size_t)(bb * H_ + h) * HD_ + d) * S_ + s0;
        *(uint2*)&outB[idx] = pkt;
      }
    }
  } else {  // fp32 out [m][n]
#pragma unroll
    for (int i = 0; i < 4; ++i) {
      const int mbase = m0 + mr + i * 16 + quad * 4;
#pragma unroll
      for (int j = 0; j < 4; ++j) {
        const int n = n0 + nc + j * 16 + lm;
#pragma unroll
        for (int r = 0; r < 4; ++r) outF[(size_t)(mbase + r) * D_ + n] = acc[i][j][r];
      }
    }
  }
}

// ---------------------------------------------------------------- flash attention v2
// S^T formulation: P^T stays in registers (C-layout == B-operand layout via
// permuted k-row tiles). Q frags in registers. BQ=128 (4 waves x 32q), BK=64.
// LDS: K 16KB + V^T 16KB, XOR-swizzled 16B chunks (<=2-way conflicts).
__global__ __launch_bounds__(256, 2) void flash_attn(
    const u16* __restrict__ Qb, const u16* __restrict__ Kb,
    const u16* __restrict__ Vtb, u16* __restrict__ attn) {
  // union: staging K(8192 u16) + Vt(8192 u16)  |  epilogue Et 128x136 u16
  __shared__ __align__(16) u16 lds[17408];
  u16* Ks  = lds;
  u16* Vts = lds + 8192;

  const int tid = threadIdx.x;
  const int lane = tid & 63, w = tid >> 6;
  const int lm = lane & 15, quad = lane >> 4;
  const int qb = 15 - blockIdx.x;  // heavy q-blocks first
  const int bh = blockIdx.y;
  const int bb = bh >> 5, h = bh & 31;

  const u16* Qg = Qb + ((size_t)bh * S_ + qb * 128 + w * 32) * HD_;
  const u16* Kg = Kb + (size_t)bh * S_ * HD_;
  const u16* Vg = Vtb + (size_t)bh * HD_ * S_;

  // Q fragments [qt][dk]: B-operand layout (lane lm = q-row, k = quad*8+j)
  bf16x8 qf[2][4];
#pragma unroll
  for (int qt = 0; qt < 2; ++qt)
#pragma unroll
    for (int dk = 0; dk < 4; ++dk)
      qf[qt][dk] = *(const bf16x8*)(Qg + (size_t)(qt * 16 + lm) * HD_ + dk * 32 + quad * 8);

  f32x4 accO[8][2] = {};  // O^T: [dt][qt], rows d = dt*16+quad*4+r, cols q = qt*16+lm
  float m_run[2] = {-1e30f, -1e30f}, l_run[2] = {0.f, 0.f};
  const float scale = 0.08838834764831845f;  // 1/sqrt(128)
  const int nkt = 2 * qb + 2;
  const int qg0 = qb * 128 + w * 32;
  const int wq_max = qg0 + 31;

  // staging assignment (4 x 16B chunks per thread for K and V each)
  int krow[4], kch[4], vrow[4], vch[4];
#pragma unroll
  for (int it = 0; it < 4; ++it) {
    int id = tid + 256 * it;
    krow[it] = id >> 4; kch[it] = id & 15;
    vrow[it] = id >> 3; vch[it] = id & 7;
  }
  uint4 kpf[4], vpf[4];
#pragma unroll
  for (int it = 0; it < 4; ++it) {
    kpf[it] = *(const uint4*)(Kg + (size_t)krow[it] * HD_ + kch[it] * 8);
    vpf[it] = *(const uint4*)(Vg + (size_t)vrow[it] * S_ + vch[it] * 8);
  }

  for (int kt = 0; kt < nkt; ++kt) {
    const int k0 = kt * 64;
    __syncthreads();
#pragma unroll
    for (int it = 0; it < 4; ++it) {
      *(uint4*)&Ks[(krow[it] * 16 + (kch[it] ^ (krow[it] & 15))) * 8] = kpf[it];
      *(uint4*)&Vts[(vrow[it] * 8 + (vch[it] ^ (vrow[it] & 7))) * 8] = vpf[it];
    }
    __syncthreads();
    if (kt + 1 < nkt) {  // prefetch next tile into regs (overlaps compute)
      const int k1 = k0 + 64;
#pragma unroll
      for (int it = 0; it < 4; ++it) {
        kpf[it] = *(const uint4*)(Kg + (size_t)(k1 + krow[it]) * HD_ + kch[it] * 8);
        vpf[it] = *(const uint4*)(Vg + (size_t)vrow[it] * S_ + k1 + vch[it] * 8);
      }
    }
    const bool active = (k0 <= wq_max);
    if (active) {
      // ---- S^T = K * Q^T ; tile t rows permuted: k = (t>>1)*32 + quad*8 + (t&1)*4 + r
      f32x4 sacc[2][4] = {};  // [qt][t]
#pragma unroll
      for (int dk = 0; dk < 4; ++dk) {
        bf16x8 kf[4];
#pragma unroll
        for (int t = 0; t < 4; ++t) {
          int row = (t >> 1) * 32 + ((lm >> 2) * 8) + ((t & 1) * 4) + (lm & 3);
          int ch = (dk * 4 + quad) ^ (row & 15);
          kf[t] = *(const bf16x8*)&Ks[(row * 16 + ch) * 8];
        }
#pragma unroll
        for (int t = 0; t < 4; ++t)
#pragma unroll
          for (int qt = 0; qt < 2; ++qt)
            sacc[qt][t] = __builtin_amdgcn_mfma_f32_16x16x32_bf16(kf[t], qf[qt][dk], sacc[qt][t], 0, 0, 0);
      }
      // ---- causal mask (wave-uniform branch; only trailing tiles)
      if (k0 + 63 > qg0) {
#pragma unroll
        for (int qt = 0; qt < 2; ++qt) {
          int q = qg0 + qt * 16 + lm;
#pragma unroll
          for (int t = 0; t < 4; ++t) {
            int kb = k0 + (t >> 1) * 32 + quad * 8 + (t & 1) * 4;
#pragma unroll
            for (int r = 0; r < 4; ++r)
              if (kb + r > q) sacc[qt][t][r] = -1e30f;
          }
        }
      }
      // ---- online softmax (per lane q = qt*16+lm; cross-quad = full k coverage)
      bf16x8 pf[2][2];  // P^T frags [kc][qt] -- B-operand for PV, from regs
      float alpha[2];
#pragma unroll
      for (int qt = 0; qt < 2; ++qt) {
        float tmax = sacc[qt][0][0];
#pragma unroll
        for (int t = 0; t < 4; ++t)
#pragma unroll
          for (int r = 0; r < 4; ++r) tmax = fmaxf(tmax, sacc[qt][t][r]);
        tmax = fmaxf(tmax, __shfl_xor(tmax, 16));
        tmax = fmaxf(tmax, __shfl_xor(tmax, 32));
        float mnew = fmaxf(m_run[qt], tmax);
        alpha[qt] = __expf((m_run[qt] - mnew) * scale);
        m_run[qt] = mnew;
        float ms = mnew * scale;
        float rs = 0.f;
#pragma unroll
        for (int t = 0; t < 4; ++t)
#pragma unroll
          for (int r = 0; r < 4; ++r) {
            float p = __expf(fmaf(sacc[qt][t][r], scale, -ms));
            sacc[qt][t][r] = p;
            rs += p;
          }
        rs += __shfl_xor(rs, 16);
        rs += __shfl_xor(rs, 32);
        l_run[qt] = l_run[qt] * alpha[qt] + rs;
#pragma unroll
        for (int kc = 0; kc < 2; ++kc)
#pragma unroll
          for (int j = 0; j < 4; ++j) {
            pf[kc][qt][j]     = (__bf16)sacc[qt][2 * kc][j];
            pf[kc][qt][j + 4] = (__bf16)sacc[qt][2 * kc + 1][j];
          }
      }
      // ---- O^T = V^T * P^T (rescale then accumulate)
#pragma unroll
      for (int dt = 0; dt < 8; ++dt)
#pragma unroll
        for (int qt = 0; qt < 2; ++qt)
#pragma unroll
          for (int r = 0; r < 4; ++r) accO[dt][qt][r] *= alpha[qt];
#pragma unroll
      for (int kc = 0; kc < 2; ++kc)
#pragma unroll
        for (int dt = 0; dt < 8; ++dt) {
          int row = dt * 16 + lm;
          int ch = (kc * 4 + quad) ^ (row & 7);
          bf16x8 vf = *(const bf16x8*)&Vts[(row * 8 + ch) * 8];
#pragma unroll
          for (int qt = 0; qt < 2; ++qt)
            accO[dt][qt] = __builtin_amdgcn_mfma_f32_16x16x32_bf16(vf, pf[kc][qt], accO[dt][qt], 0, 0, 0);
        }
    }
  }

  // ---- epilogue: transpose O^T -> O via LDS (reuse staging space), coalesced store
  __syncthreads();  // all waves done reading K/V
  u16* Et = lds;    // 128 q-rows x 136 (pad 8: stride 68 dw, ~2-4 way once)
  float inv[2] = {1.f / l_run[0], 1.f / l_run[1]};
#pragma unroll
  for (int dt = 0; dt < 8; ++dt)
#pragma unroll
    for (int qt = 0; qt < 2; ++qt) {
      const int rowq = w * 32 + qt * 16 + lm;
#pragma unroll
      for (int rp = 0; rp < 2; ++rp) {
        float a0 = accO[dt][qt][rp * 2] * inv[qt];
        float a1 = accO[dt][qt][rp * 2 + 1] * inv[qt];
        unsigned pkt = rne_bf16(a0) | (rne_bf16(a1) << 16);
        *(unsigned*)&Et[rowq * 136 + dt * 16 + quad * 4 + rp * 2] = pkt;
      }
    }
  // wave-private region: compiler's lgkmcnt ordering suffices, no barrier
  const int rloc = w * 32 + (lane >> 1);
  const int half = lane & 1;
  const size_t gbase = (size_t)(bb * S_ + qb * 128 + rloc) * D_ + h * 128 + half * 64;
#pragma unroll
  for (int k = 0; k < 8; ++k) {
    uint4 vv = *(const uint4*)&Et[rloc * 136 + half * 64 + k * 8];
    *(uint4*)&attn[gbase + k * 8] = vv;
  }
}

// ---------------------------------------------------------------- launch
extern "C" void kernel_launch(void* const* d_in, const int* in_sizes, int n_in,
                              void* d_out, int out_size, void* d_ws, size_t ws_size,
                              hipStream_t stream) {
  const float* x  = (const float*)d_in[0];
  const float* fc = (const float*)d_in[1];
  const float* fs = (const float*)d_in[2];
  // d_in[3] = mask (causal, handled analytically)
  const float* wq = (const float*)d_in[4];
  const float* wk = (const float*)d_in[5];
  const float* wv = (const float*)d_in[6];
  const float* wo = (const float*)d_in[7];
  float* out = (float*)d_out;

  char* ws = (char*)d_ws;
  const size_t SZ = (size_t)B_ * S_ * D_ * 2;
  u16* xb  = (u16*)(ws);
  u16* wqb = (u16*)(ws + SZ);
  u16* wkb = (u16*)(ws + 2 * SZ);
  u16* wvb = (u16*)(ws + 3 * SZ);
  u16* Qb  = (u16*)(ws + 4 * SZ);
  u16* Kb  = (u16*)(ws + 5 * SZ);
  u16* Vtb = (u16*)(ws + 6 * SZ);
  u16* attn = xb;
  u16* wob  = wqb;

  dim3 blk(256);
  const int n8 = (B_ * S_ * D_) / 8;
  convert_bf16<<<n8 / 256, blk, 0, stream>>>(x, xb, n8);
  convert_bf16<<<n8 / 256, blk, 0, stream>>>(wq, wqb, n8);
  convert_bf16<<<n8 / 256, blk, 0, stream>>>(wk, wkb, n8);
  convert_bf16<<<n8 / 256, blk, 0, stream>>>(wv, wvb, n8);

  dim3 g1(32, 32);
  gemm_bt<1><<<g1, blk, 0, stream>>>(xb, wqb, Qb, nullptr, fc, fs);
  gemm_bt<1><<<g1, blk, 0, stream>>>(xb, wkb, Kb, nullptr, fc, fs);
  gemm_bt<3><<<g1, blk, 0, stream>>>(xb, wvb, Vtb, nullptr, nullptr, nullptr);

  dim3 g2(16, 64);
  flash_attn<<<g2, blk, 0, stream>>>(Qb, Kb, Vtb, attn);

  convert_bf16<<<n8 / 256, blk, 0, stream>>>(wo, wob, n8);
  gemm_bt<4><<<g1, blk, 0, stream>>>(attn, wob, nullptr, out, nullptr, nullptr);
}

// Round 3
// 1258.357 us; speedup vs baseline: 1.2113x; 1.2113x over previous
//
#include <hip/hip_runtime.h>
#include <hip/hip_bf16.h>
#include <math.h>

typedef unsigned short u16;
typedef __bf16 bf16x8 __attribute__((ext_vector_type(8)));
typedef float f32x4 __attribute__((ext_vector_type(4)));

#define B_  2
#define S_  2048
#define D_  4096
#define H_  32
#define HD_ 128

__device__ __forceinline__ unsigned rne_bf16(float x) {
  unsigned u = __float_as_uint(x);
  return (u + 0x7fffu + ((u >> 16) & 1u)) >> 16;
}

__device__ __forceinline__ void async16(void* lds, const void* g) {
  __builtin_amdgcn_global_load_lds(
      (__attribute__((address_space(1))) void*)(g),
      (__attribute__((address_space(3))) void*)(lds), 16, 0, 0);
}

// ---------------------------------------------------------------- convert
__global__ __launch_bounds__(256) void convert_bf16(
    const float* __restrict__ src, u16* __restrict__ dst, int n8) {
  int i = blockIdx.x * 256 + threadIdx.x;
  if (i >= n8) return;
  const float4* s = (const float4*)src + (size_t)i * 2;
  float4 a = s[0], b = s[1];
  uint4 o;
  o.x = rne_bf16(a.x) | (rne_bf16(a.y) << 16);
  o.y = rne_bf16(a.z) | (rne_bf16(a.w) << 16);
  o.z = rne_bf16(b.x) | (rne_bf16(b.y) << 16);
  o.w = rne_bf16(b.z) | (rne_bf16(b.w) << 16);
  ((uint4*)dst)[i] = o;
}

// ---------------------------------------------------------------- GEMM (A row-major MxK, B row-major NxK, C = A*B^T)
template <int MODE>
__global__ __launch_bounds__(256) void gemm_bt(
    const u16* __restrict__ A, const u16* __restrict__ Bw,
    u16* __restrict__ outB, float* __restrict__ outF,
    const float* __restrict__ fc, const float* __restrict__ fs) {
  __shared__ u16 As[128 * 32];
  __shared__ u16 Bs[128 * 32];
  const int tid  = threadIdx.x;
  const int lane = tid & 63;
  const int wave = tid >> 6;
  const int lm   = lane & 15, quad = lane >> 4;
  const int m0 = blockIdx.x * 128, n0 = blockIdx.y * 128;
  const int mr = (wave >> 1) * 64, nc = (wave & 1) * 64;
  const int K = 4096;

  const int c0 = tid, c1 = tid + 256;
  const int r0 = c0 >> 2, kc0 = ((c0 & 3) ^ ((c0 >> 4) & 3)) * 8;
  const int r1 = c1 >> 2, kc1 = ((c1 & 3) ^ ((c1 >> 4) & 3)) * 8;
  const u16* Ag0 = A + (size_t)(m0 + r0) * K + kc0;
  const u16* Ag1 = A + (size_t)(m0 + r1) * K + kc1;
  const u16* Bg0 = Bw + (size_t)(n0 + r0) * K + kc0;
  const u16* Bg1 = Bw + (size_t)(n0 + r1) * K + kc1;

  const int koff = (quad ^ ((lm >> 2) & 3)) * 8;

  f32x4 acc[4][4] = {};

  for (int kb = 0; kb < K; kb += 32) {
    async16(&As[c0 * 8], Ag0 + kb);
    async16(&As[c1 * 8], Ag1 + kb);
    async16(&Bs[c0 * 8], Bg0 + kb);
    async16(&Bs[c1 * 8], Bg1 + kb);
    __syncthreads();
    bf16x8 af[4], bfr[4];
#pragma unroll
    for (int i = 0; i < 4; ++i) af[i] = *(const bf16x8*)&As[(mr + i * 16 + lm) * 32 + koff];
#pragma unroll
    for (int j = 0; j < 4; ++j) bfr[j] = *(const bf16x8*)&Bs[(nc + j * 16 + lm) * 32 + koff];
#pragma unroll
    for (int i = 0; i < 4; ++i)
#pragma unroll
      for (int j = 0; j < 4; ++j)
        acc[i][j] = __builtin_amdgcn_mfma_f32_16x16x32_bf16(af[i], bfr[j], acc[i][j], 0, 0, 0);
    __syncthreads();
  }

  if (MODE == 1) {  // RoPE -> [bh][s][d]
#pragma unroll
    for (int i = 0; i < 4; ++i) {
      const int mbase = m0 + mr + i * 16 + quad * 4;
#pragma unroll
      for (int j = 0; j < 4; ++j) {
        const int n = n0 + nc + j * 16 + lm;
        const int h = n >> 7, d = n & 127, ir = d >> 1;
#pragma unroll
        for (int r = 0; r < 4; ++r) {
          const int m = mbase + r;
          const int s = m & (S_ - 1);
          const int bb = m >> 11;
          float v = acc[i][j][r];
          float p = __shfl_xor(v, 1);
          float cv = fc[s * (HD_ / 2) + ir];
          float sv = fs[s * (HD_ / 2) + ir];
          float o = ((lane & 1) == 0) ? (v * cv - p * sv) : (p * sv + v * cv);
          float po = __shfl_xor(o, 1);
          if ((lane & 1) == 0) {
            unsigned pkt = rne_bf16(o) | (rne_bf16(po) << 16);
            size_t idx = (((size_t)(bb * H_ + h) * S_ + s) * HD_ + d) >> 1;
            ((unsigned*)outB)[idx] = pkt;
          }
        }
      }
    }
  } else if (MODE == 3) {  // V^T -> [bh][d][s]
#pragma unroll
    for (int i = 0; i < 4; ++i) {
      const int mbase = m0 + mr + i * 16 + quad * 4;
      const int s0 = mbase & (S_ - 1);
      const int bb = mbase >> 11;
#pragma unroll
      for (int j = 0; j < 4; ++j) {
        const int n = n0 + nc + j * 16 + lm;
        const int h = n >> 7, d = n & 127;
        uint2 pkt;
        pkt.x = rne_bf16(acc[i][j][0]) | (rne_bf16(acc[i][j][1]) << 16);
        pkt.y = rne_bf16(acc[i][j][2]) | (rne_bf16(acc[i][j][3]) << 16);
        size_t idx = ((size_t)(bb * H_ + h) * HD_ + d) * S_ + s0;
        *(uint2*)&outB[idx] = pkt;
      }
    }
  } else {  // fp32 out [m][n]
#pragma unroll
    for (int i = 0; i < 4; ++i) {
      const int mbase = m0 + mr + i * 16 + quad * 4;
#pragma unroll
      for (int j = 0; j < 4; ++j) {
        const int n = n0 + nc + j * 16 + lm;
#pragma unroll
        for (int r = 0; r < 4; ++r) outF[(size_t)(mbase + r) * D_ + n] = acc[i][j][r];
      }
    }
  }
}

// ---------------------------------------------------------------- flash attention v3
// S^T formulation (P^T in registers), Q frags in registers, BQ=128, BK=64.
// K/V staged via global_load_lds into DOUBLE-BUFFERED LDS (no VGPR prefetch ->
// no spills). Global-side XOR swizzle keeps frag reads <=2-way conflict.
__global__ __launch_bounds__(256, 2) void flash_attn(
    const u16* __restrict__ Qb, const u16* __restrict__ Kb,
    const u16* __restrict__ Vtb, u16* __restrict__ attn) {
  // 2 buffers x (K 8192 u16 + V 8192 u16) = 64 KB; epilogue Et reuses buf0.
  __shared__ __align__(16) u16 lds[32768];

  const int tid = threadIdx.x;
  const int lane = tid & 63, w = tid >> 6;
  const int lm = lane & 15, quad = lane >> 4;
  const int qb = 15 - blockIdx.x;  // heavy q-blocks first
  const int bh = blockIdx.y;
  const int bb = bh >> 5, h = bh & 31;

  const u16* Qg = Qb + ((size_t)bh * S_ + qb * 128 + w * 32) * HD_;
  const u16* Kg = Kb + (size_t)bh * S_ * HD_;
  const u16* Vg = Vtb + (size_t)bh * HD_ * S_;

  // global source pointers for staging: LDS chunk c holds global chunk
  //   K: (row=c>>4, gch=(c&15)^(row&15));  V: (row=c>>3, gch=(c&7)^(row&7))
  const u16* kp[4];
  const u16* vp[4];
#pragma unroll
  for (int it = 0; it < 4; ++it) {
    int c = tid + 256 * it;
    int kr = c >> 4, kc = (c & 15) ^ (kr & 15);
    kp[it] = Kg + (size_t)kr * HD_ + kc * 8;
    int vr = c >> 3, vc = (c & 7) ^ (vr & 7);
    vp[it] = Vg + (size_t)vr * S_ + vc * 8;
  }

  // Q fragments [qt][dk]: B-operand layout (lane lm = q-row, k = quad*8+j)
  bf16x8 qf[2][4];
#pragma unroll
  for (int qt = 0; qt < 2; ++qt)
#pragma unroll
    for (int dk = 0; dk < 4; ++dk)
      qf[qt][dk] = *(const bf16x8*)(Qg + (size_t)(qt * 16 + lm) * HD_ + dk * 32 + quad * 8);

  f32x4 accO[8][2] = {};  // O^T: rows d = dt*16+quad*4+r, cols q = qt*16+lm
  float m_run[2] = {-1e30f, -1e30f}, l_run[2] = {0.f, 0.f};
  const float scale = 0.08838834764831845f;  // 1/sqrt(128)
  const int nkt = 2 * qb + 2;
  const int qg0 = qb * 128 + w * 32;
  const int wq_max = qg0 + 31;

  // preload tile 0 into buffer 0
#pragma unroll
  for (int it = 0; it < 4; ++it) {
    async16(&lds[(tid + 256 * it) * 8], kp[it]);
    async16(&lds[8192 + (tid + 256 * it) * 8], vp[it]);
  }

  for (int kt = 0; kt < nkt; ++kt) {
    const int k0 = kt * 64;
    const int cur = (kt & 1) * 16384;
    __syncthreads();  // drains vmcnt: buf[cur] ready; buf[nxt] free
    if (kt + 1 < nkt) {
      const int nxt = cur ^ 16384;
      const size_t koK = (size_t)(kt + 1) * 64 * HD_;
      const size_t koV = (size_t)(kt + 1) * 64;
#pragma unroll
      for (int it = 0; it < 4; ++it) {
        async16(&lds[nxt + (tid + 256 * it) * 8], kp[it] + koK);
        async16(&lds[nxt + 8192 + (tid + 256 * it) * 8], vp[it] + koV);
      }
    }
    if (k0 <= wq_max) {
      const u16* Ks = lds + cur;
      const u16* Vts = lds + cur + 8192;
      // ---- S^T = K * Q^T ; tile t rows: k = (t>>1)*32 + quad*8 + (t&1)*4 + r
      f32x4 sacc[2][4] = {};  // [qt][t]
#pragma unroll
      for (int dk = 0; dk < 4; ++dk) {
        bf16x8 kf[4];
#pragma unroll
        for (int t = 0; t < 4; ++t) {
          int row = (t >> 1) * 32 + ((lm >> 2) * 8) + ((t & 1) * 4) + (lm & 3);
          int ch = (dk * 4 + quad) ^ (row & 15);
          kf[t] = *(const bf16x8*)&Ks[(row * 16 + ch) * 8];
        }
#pragma unroll
        for (int t = 0; t < 4; ++t)
#pragma unroll
          for (int qt = 0; qt < 2; ++qt)
            sacc[qt][t] = __builtin_amdgcn_mfma_f32_16x16x32_bf16(kf[t], qf[qt][dk], sacc[qt][t], 0, 0, 0);
      }
      // ---- causal mask (wave-uniform branch; only trailing tiles)
      if (k0 + 63 > qg0) {
#pragma unroll
        for (int qt = 0; qt < 2; ++qt) {
          int q = qg0 + qt * 16 + lm;
#pragma unroll
          for (int t = 0; t < 4; ++t) {
            int kb = k0 + (t >> 1) * 32 + quad * 8 + (t & 1) * 4;
#pragma unroll
            for (int r = 0; r < 4; ++r)
              if (kb + r > q) sacc[qt][t][r] = -1e30f;
          }
        }
      }
      // ---- online softmax (lane q = qt*16+lm; cross-quad shuffles = full k)
      bf16x8 pf[2][2];  // P^T frags [kc][qt] -- B-operand for PV
      float alpha[2];
#pragma unroll
      for (int qt = 0; qt < 2; ++qt) {
        float tmax = sacc[qt][0][0];
#pragma unroll
        for (int t = 0; t < 4; ++t)
#pragma unroll
          for (int r = 0; r < 4; ++r) tmax = fmaxf(tmax, sacc[qt][t][r]);
        tmax = fmaxf(tmax, __shfl_xor(tmax, 16));
        tmax = fmaxf(tmax, __shfl_xor(tmax, 32));
        float mnew = fmaxf(m_run[qt], tmax);
        alpha[qt] = __expf((m_run[qt] - mnew) * scale);
        m_run[qt] = mnew;
        float ms = mnew * scale;
        float rs = 0.f;
#pragma unroll
        for (int t = 0; t < 4; ++t)
#pragma unroll
          for (int r = 0; r < 4; ++r) {
            float p = __expf(fmaf(sacc[qt][t][r], scale, -ms));
            sacc[qt][t][r] = p;
            rs += p;
          }
        rs += __shfl_xor(rs, 16);
        rs += __shfl_xor(rs, 32);
        l_run[qt] = l_run[qt] * alpha[qt] + rs;
#pragma unroll
        for (int kc = 0; kc < 2; ++kc)
#pragma unroll
          for (int j = 0; j < 4; ++j) {
            pf[kc][qt][j]     = (__bf16)sacc[qt][2 * kc][j];
            pf[kc][qt][j + 4] = (__bf16)sacc[qt][2 * kc + 1][j];
          }
      }
      // ---- O^T = V^T * P^T (rescale then accumulate)
#pragma unroll
      for (int dt = 0; dt < 8; ++dt)
#pragma unroll
        for (int qt = 0; qt < 2; ++qt)
#pragma unroll
          for (int r = 0; r < 4; ++r) accO[dt][qt][r] *= alpha[qt];
#pragma unroll
      for (int kc = 0; kc < 2; ++kc)
#pragma unroll
        for (int dt = 0; dt < 8; ++dt) {
          int row = dt * 16 + lm;
          int ch = (kc * 4 + quad) ^ (row & 7);
          bf16x8 vf = *(const bf16x8*)&Vts[(row * 8 + ch) * 8];
#pragma unroll
          for (int qt = 0; qt < 2; ++qt)
            accO[dt][qt] = __builtin_amdgcn_mfma_f32_16x16x32_bf16(vf, pf[kc][qt], accO[dt][qt], 0, 0, 0);
        }
    }
  }

  // ---- epilogue: transpose O^T -> O via LDS (reuse buf0), coalesced store
  __syncthreads();  // all waves done reading K/V
  u16* Et = lds;    // 128 q-rows x 136 u16
  float inv[2] = {1.f / l_run[0], 1.f / l_run[1]};
#pragma unroll
  for (int dt = 0; dt < 8; ++dt)
#pragma unroll
    for (int qt = 0; qt < 2; ++qt) {
      const int rowq = w * 32 + qt * 16 + lm;
#pragma unroll
      for (int rp = 0; rp < 2; ++rp) {
        float a0 = accO[dt][qt][rp * 2] * inv[qt];
        float a1 = accO[dt][qt][rp * 2 + 1] * inv[qt];
        unsigned pkt = rne_bf16(a0) | (rne_bf16(a1) << 16);
        *(unsigned*)&Et[rowq * 136 + dt * 16 + quad * 4 + rp * 2] = pkt;
      }
    }
  // wave-private region: compiler's lgkmcnt ordering suffices, no barrier
  const int rloc = w * 32 + (lane >> 1);
  const int half = lane & 1;
  const size_t gbase = (size_t)(bb * S_ + qb * 128 + rloc) * D_ + h * 128 + half * 64;
#pragma unroll
  for (int k = 0; k < 8; ++k) {
    uint4 vv = *(const uint4*)&Et[rloc * 136 + half * 64 + k * 8];
    *(uint4*)&attn[gbase + k * 8] = vv;
  }
}

// ---------------------------------------------------------------- launch
extern "C" void kernel_launch(void* const* d_in, const int* in_sizes, int n_in,
                              void* d_out, int out_size, void* d_ws, size_t ws_size,
                              hipStream_t stream) {
  const float* x  = (const float*)d_in[0];
  const float* fc = (const float*)d_in[1];
  const float* fs = (const float*)d_in[2];
  // d_in[3] = mask (causal, handled analytically)
  const float* wq = (const float*)d_in[4];
  const float* wk = (const float*)d_in[5];
  const float* wv = (const float*)d_in[6];
  const float* wo = (const float*)d_in[7];
  float* out = (float*)d_out;

  char* ws = (char*)d_ws;
  const size_t SZ = (size_t)B_ * S_ * D_ * 2;
  u16* xb  = (u16*)(ws);
  u16* wqb = (u16*)(ws + SZ);
  u16* wkb = (u16*)(ws + 2 * SZ);
  u16* wvb = (u16*)(ws + 3 * SZ);
  u16* Qb  = (u16*)(ws + 4 * SZ);
  u16* Kb  = (u16*)(ws + 5 * SZ);
  u16* Vtb = (u16*)(ws + 6 * SZ);
  u16* attn = xb;
  u16* wob  = wqb;

  dim3 blk(256);
  const int n8 = (B_ * S_ * D_) / 8;
  convert_bf16<<<n8 / 256, blk, 0, stream>>>(x, xb, n8);
  convert_bf16<<<n8 / 256, blk, 0, stream>>>(wq, wqb, n8);
  convert_bf16<<<n8 / 256, blk, 0, stream>>>(wk, wkb, n8);
  convert_bf16<<<n8 / 256, blk, 0, stream>>>(wv, wvb, n8);

  dim3 g1(32, 32);
  gemm_bt<1><<<g1, blk, 0, stream>>>(xb, wqb, Qb, nullptr, fc, fs);
  gemm_bt<1><<<g1, blk, 0, stream>>>(xb, wkb, Kb, nullptr, fc, fs);
  gemm_bt<3><<<g1, blk, 0, stream>>>(xb, wvb, Vtb, nullptr, nullptr, nullptr);

  dim3 g2(16, 64);
  flash_attn<<<g2, blk, 0, stream>>>(Qb, Kb, Vtb, attn);

  convert_bf16<<<n8 / 256, blk, 0, stream>>>(wo, wob, n8);
  gemm_bt<4><<<g1, blk, 0, stream>>>(attn, wob, nullptr, out, nullptr, nullptr);
}